// Round 1
// baseline (122.691 us; speedup 1.0000x reference)
//
#include <hip/hip_runtime.h>
#include <math.h>

// Chamfer loss, two 16384x3 fp32 clouds.
// Pass 1: per-query partial min of (||b||^2 - 2 a.b) over a DB slice (S slices).
// Pass 2: combine slices, add ||a||^2, clamp, sqrt, block-reduce partial sums.
// Pass 3: fold block partials -> scalar * 5/N.

#define TILE 2048   // DB points per LDS tile: 2048 * 16B = 32 KB

__global__ __launch_bounds__(256) void chamfer_partial_min(
    const float* __restrict__ state_x, const float* __restrict__ target,
    float* __restrict__ mins, int N, int S)
{
    const int tid = threadIdx.x;
    const int block_q = blockIdx.x / S;     // which 256-query chunk
    const int s = blockIdx.x % S;           // which DB slice
    const int qi = block_q * 256 + tid;     // global query id in [0, 2N)

    const float* qcloud;
    const float* db;
    int qidx;
    if (qi < N) { qcloud = target;  db = state_x; qidx = qi;     }  // dist1
    else        { qcloud = state_x; db = target;  qidx = qi - N; }  // dist2

    const float qx = qcloud[3 * qidx + 0];
    const float qy = qcloud[3 * qidx + 1];
    const float qz = qcloud[3 * qidx + 2];
    const float m2x = -2.0f * qx, m2y = -2.0f * qy, m2z = -2.0f * qz;

    __shared__ float4 tile[TILE];

    const int sliceN = N / S;
    const int base0 = s * sliceN;
    float m0 = 3.0e38f, m1 = 3.0e38f;

    for (int t0 = 0; t0 < sliceN; t0 += TILE) {
        // Stage tile: (bx, by, bz, ||b||^2) per point.
        for (int p = tid; p < TILE; p += 256) {
            const int g = base0 + t0 + p;
            const float bx = db[3 * g + 0];
            const float by = db[3 * g + 1];
            const float bz = db[3 * g + 2];
            tile[p] = make_float4(bx, by, bz, bx * bx + by * by + bz * bz);
        }
        __syncthreads();

        // Inner loop: 4 VALU ops per DB point. Broadcast ds_read_b128 per point.
        #pragma unroll 4
        for (int j = 0; j < TILE; j += 2) {
            const float4 b0 = tile[j];
            const float4 b1 = tile[j + 1];
            const float d0 = fmaf(b0.z, m2z, fmaf(b0.y, m2y, fmaf(b0.x, m2x, b0.w)));
            const float d1 = fmaf(b1.z, m2z, fmaf(b1.y, m2y, fmaf(b1.x, m2x, b1.w)));
            m0 = fminf(m0, d0);
            m1 = fminf(m1, d1);
        }
        __syncthreads();
    }

    mins[(size_t)s * (size_t)(2 * N) + qi] = fminf(m0, m1);
}

__global__ __launch_bounds__(256) void chamfer_sqrt_sum(
    const float* __restrict__ state_x, const float* __restrict__ target,
    const float* __restrict__ mins, float* __restrict__ partials, int N, int S)
{
    const int tid = threadIdx.x;
    const int qi = blockIdx.x * 256 + tid;

    const float* qcloud = (qi < N) ? target : state_x;
    const int qidx = (qi < N) ? qi : qi - N;
    const float qx = qcloud[3 * qidx + 0];
    const float qy = qcloud[3 * qidx + 1];
    const float qz = qcloud[3 * qidx + 2];
    const float a2 = qx * qx + qy * qy + qz * qz;

    float m = 3.0e38f;
    for (int s = 0; s < S; ++s)
        m = fminf(m, mins[(size_t)s * (size_t)(2 * N) + qi]);

    float v = sqrtf(fmaxf(a2 + m, 0.0f));

    // wave64 shuffle reduce, then cross-wave via LDS
    for (int off = 32; off > 0; off >>= 1) v += __shfl_down(v, off, 64);
    __shared__ float wsum[4];
    if ((tid & 63) == 0) wsum[tid >> 6] = v;
    __syncthreads();
    if (tid == 0)
        partials[blockIdx.x] = wsum[0] + wsum[1] + wsum[2] + wsum[3];
}

__global__ void chamfer_final(const float* __restrict__ partials,
                              float* __restrict__ out, int nPartials, int N)
{
    const int tid = threadIdx.x;  // 128 threads
    float v = (tid < nPartials) ? partials[tid] : 0.0f;
    for (int off = 32; off > 0; off >>= 1) v += __shfl_down(v, off, 64);
    __shared__ float w[2];
    if ((tid & 63) == 0) w[tid >> 6] = v;
    __syncthreads();
    if (tid == 0)
        out[0] = (w[0] + w[1]) * 5.0f / (float)N;   // (mean1+mean2)*0.5*10
}

extern "C" void kernel_launch(void* const* d_in, const int* in_sizes, int n_in,
                              void* d_out, int out_size, void* d_ws, size_t ws_size,
                              hipStream_t stream)
{
    const float* state_x = (const float*)d_in[0];
    const float* target  = (const float*)d_in[1];
    float* out = (float*)d_out;

    const int N = in_sizes[0] / 3;          // 16384
    const int nQBlocks = (2 * N) / 256;     // 128

    // Pick DB-slice count S so ws fits: S*2N floats (mins) + nQBlocks floats.
    int S = 4;
    while (S > 1 &&
           ((size_t)S * (size_t)(2 * N) + (size_t)nQBlocks) * sizeof(float) > ws_size)
        S >>= 1;

    float* mins = (float*)d_ws;
    float* partials = mins + (size_t)S * (size_t)(2 * N);

    chamfer_partial_min<<<nQBlocks * S, 256, 0, stream>>>(state_x, target, mins, N, S);
    chamfer_sqrt_sum<<<nQBlocks, 256, 0, stream>>>(state_x, target, mins, partials, N, S);
    chamfer_final<<<1, 128, 0, stream>>>(partials, out, nQBlocks, N);
}